// Round 4
// baseline (533.411 us; speedup 1.0000x reference)
//
#include <hip/hip_runtime.h>
#include <math.h>

// ---------------------------------------------------------------------------
// MegaCartTensorOut: fused equivariant TP block, MFMA (bf16) edition.
//
// d_ws layout:
//   floats [0,438): CG tensors + QB (same as before)
//   bytes [2048, 2048+67584): bf16 weight fragments packed in MFMA B-order
// MFMA 16x16x32 bf16. Only layout facts relied on:
//   - A row / B col = lane&15 (k-mapping cancels when consistent on A and B)
//   - C/D: col = lane&15, row = 4*(lane>>4)+reg   [HW-verified]
// ---------------------------------------------------------------------------

#define N_CG_FLOATS 438

typedef short s16x8 __attribute__((ext_vector_type(8)));
typedef float f32x4 __attribute__((ext_vector_type(4)));

// pack region (units: shorts, from byte 2048 of ws)
#define PK_BYTE_OFF 2048
#define PK_A1 0       // 16 frags (K=128,N=64)
#define PK_W0 8192    // 8  frags (K=128,N=32), scaled 1/sqrt(128)
#define PK_W1 12288   // 4  frags (K=64, N=32), scaled 1/sqrt(64)
#define PK_W2 14336   // 2  frags (K=32, N=32), scaled 1/sqrt(32)
#define PK_A2 15360   // 36 frags (K=64, N=288)
#define PK_TOTAL 33792

// smem layout (bytes); tw aliases Asp0+Asp1 (dead by GEMM2 phase)
#define CG_OFF 0        // 438 f32
#define AS0_OFF 1792    // 32 x 128 bf16, stride 256B, swizzled
#define ASP0_OFF 9984   // 32 x 128 bf16, stride 256B
#define ASP1_OFF 18176  // 96 x 64  bf16, stride 128B (row = m*32+n)
#define ASP2_OFF 30464  // 160 x 32 bf16, stride 64B  (row = m*32+n)
#define AH_OFF 40704    // 32 x 64  bf16, stride 128B
#define Y_OFF 44800     // 32 x 288 bf16, stride 576B, plain
#define TW_OFF 9984     // 32 x 288 bf16, stride 576B, plain (alias)
#define SMEM_BYTES 63232

__device__ __forceinline__ short f2bf(float f) {
  union { float f; unsigned u; } x; x.f = f;
  unsigned r = (x.u + 0x7FFFu + ((x.u >> 16) & 1u)) >> 16;
  return (short)r;
}
__device__ __forceinline__ float bf2f(unsigned short s) {
  union { unsigned u; float f; } x; x.u = ((unsigned)s) << 16;
  return x.f;
}

// ---------------- CG setup (unchanged, verified) ----------------------------

__device__ __forceinline__ double dfact(int n) {
  double r = 1.0;
  for (int i = 2; i <= n; ++i) r *= (double)i;
  return r;
}

__device__ __forceinline__ void u_elem(int l, int i, int j, double& re, double& im) {
  re = 0.0; im = 0.0;
  const int mr = i - l, mc = j - l;
  const double is2 = 0.70710678118654752440;
  if (mr == 0) { if (mc == 0) re = 1.0; }
  else if (mr > 0) {
    if (mc == mr) re = ((mr & 1) ? -1.0 : 1.0) * is2;
    else if (mc == -mr) re = is2;
  } else {
    int m = -mr;
    if (mc == m) im = -(((m & 1) ? -1.0 : 1.0)) * is2;
    else if (mc == -m) im = is2;
  }
}

__global__ void setup_cg_par(float* __restrict__ ws) {
  const int LAs[12] = {0, 1, 2, 1, 2, 0, 2, 1, 2, 1, 1, 1};
  const int LBs[12] = {0, 1, 2, 1, 2, 2, 0, 1, 2, 1, 1, 1};
  const int LOs[12] = {0, 0, 0, 1, 1, 2, 2, 2, 2, 0, 1, 2};
  const int OFF[12] = {0, 1, 10, 35, 62, 137, 162, 187, 232, 357, 366, 393};

  const int blk = blockIdx.x;
  const int l1 = LAs[blk], l2 = LBs[blk], l3 = LOs[blk];
  const double scale = (blk >= 9) ? sqrt(2.0 * l3 + 1.0) : 1.0;
  const int n1 = 2 * l1 + 1, n2 = 2 * l2 + 1, n3 = 2 * l3 + 1;
  const int nel = n1 * n2 * n3;
  const int t = threadIdx.x;

  __shared__ double Cs[125];
  __shared__ double Rre[125], Rim[125];
  __shared__ double s_inv;
  __shared__ int s_useRe;

  if (t < nel) {
    const int i3 = t % n3, i2 = (t / n3) % n2, i1 = t / (n3 * n2);
    const int m1 = i1 - l1, m2 = i2 - l2, m3 = i3 - l3;
    double val = 0.0;
    if (m1 + m2 == m3) {
      double pre = sqrt((2.0 * l3 + 1.0) * dfact(l1 + l2 - l3) * dfact(l1 - l2 + l3) *
                        dfact(-l1 + l2 + l3) / dfact(l1 + l2 + l3 + 1));
      pre *= sqrt(dfact(l3 + m3) * dfact(l3 - m3) * dfact(l1 - m1) * dfact(l1 + m1) *
                  dfact(l2 - m2) * dfact(l2 + m2));
      double s = 0.0;
      for (int k = 0; k <= l1 + l2 - l3; ++k) {
        int d1 = l1 + l2 - l3 - k, d2 = l1 - m1 - k, d3 = l2 + m2 - k;
        int d4 = l3 - l2 + m1 + k, d5 = l3 - l1 - m2 + k;
        if (d1 < 0 || d2 < 0 || d3 < 0 || d4 < 0 || d5 < 0) continue;
        double prod = dfact(k) * dfact(d1) * dfact(d2) * dfact(d3) * dfact(d4) * dfact(d5);
        s += ((k & 1) ? -1.0 : 1.0) / prod;
      }
      val = pre * s;
    }
    Cs[t] = val;
  }
  __syncthreads();

  if (t < nel) {
    const int c = t % n3, bb = (t / n3) % n2, a = t / (n3 * n2);
    double sr_ = 0.0, si_ = 0.0;
    for (int m = 0; m < n1; ++m) {
      double u1r, u1i;
      u_elem(l1, a, m, u1r, u1i);
      if (u1r == 0.0 && u1i == 0.0) continue;
      for (int nn = 0; nn < n2; ++nn) {
        double u2r, u2i;
        u_elem(l2, bb, nn, u2r, u2i);
        double t12r = u1r * u2r - u1i * u2i;
        double t12i = u1r * u2i + u1i * u2r;
        if (t12r == 0.0 && t12i == 0.0) continue;
        for (int o = 0; o < n3; ++o) {
          double cgv = Cs[(m * n2 + nn) * n3 + o];
          if (cgv == 0.0) continue;
          double u3r, u3i;
          u_elem(l3, c, o, u3r, u3i);
          sr_ += (t12r * u3r + t12i * u3i) * cgv;
          si_ += (t12i * u3r - t12r * u3i) * cgv;
        }
      }
    }
    Rre[t] = sr_;
    Rim[t] = si_;
  }
  __syncthreads();

  if (t == 0) {
    double maxRe = 0.0, maxIm = 0.0;
    for (int e = 0; e < nel; ++e) {
      maxRe = fmax(maxRe, fabs(Rre[e]));
      maxIm = fmax(maxIm, fabs(Rim[e]));
    }
    int useRe = (maxRe >= maxIm) ? 1 : 0;
    double nrm = 0.0;
    for (int e = 0; e < nel; ++e) {
      double vv = useRe ? Rre[e] : Rim[e];
      nrm += vv * vv;
    }
    s_useRe = useRe;
    s_inv = scale / sqrt(nrm);
  }
  __syncthreads();

  if (t < nel) {
    double vv = s_useRe ? Rre[t] : Rim[t];
    ws[OFF[blk] + t] = (float)(vv * s_inv);
  }
}

// ---------------- weight fragment packing -----------------------------------
// B matrix [K][N] row-major -> frag (kt,nt): lane l, j: B[kt*32+8*(l>>4)+j][nt*16+(l&15)]
__global__ void pack_weights(const float* __restrict__ A1, const float* __restrict__ W0,
                             const float* __restrict__ W1, const float* __restrict__ W2,
                             const float* __restrict__ A2, float* __restrict__ ws) {
  unsigned short* pk = (unsigned short*)((char*)ws + PK_BYTE_OFF);
  int e = blockIdx.x * 256 + threadIdx.x;
  if (e >= PK_TOTAL) return;
  const float* src;
  int N, off;
  float scale;
  if (e < PK_W0)      { src = A1; N = 64;  off = PK_A1; scale = 1.f; }
  else if (e < PK_W1) { src = W0; N = 32;  off = PK_W0; scale = 0.08838834764831845f; }
  else if (e < PK_W2) { src = W1; N = 32;  off = PK_W1; scale = 0.125f; }
  else if (e < PK_A2) { src = W2; N = 32;  off = PK_W2; scale = 0.17677669529663687f; }
  else                { src = A2; N = 288; off = PK_A2; scale = 1.f; }
  int local = e - off;
  int frag = local >> 9;
  int l = (local >> 3) & 63;
  int j = local & 7;
  int ntn = N >> 4;
  int kt = frag / ntn, nt = frag - kt * ntn;
  int k = kt * 32 + 8 * (l >> 4) + j;
  int c = nt * 16 + (l & 15);
  pk[e] = (unsigned short)f2bf(src[k * N + c] * scale);
}

// ---------------- main fused kernel ------------------------------------------

__device__ __forceinline__ void sw_st16(char* sm, int base, int strideB, int r, int c, short v) {
  int byte = base + r * strideB + c * 2;
  byte ^= (r & 7) << 4;
  *(short*)(sm + byte) = v;
}
__device__ __forceinline__ s16x8 sw_lda(const char* sm, int base, int strideB, int row0, int k0,
                                        int lane) {
  int r = row0 + (lane & 15);
  int byte = base + r * strideB + (k0 + 8 * (lane >> 4)) * 2;
  byte ^= (r & 7) << 4;
  return *(const s16x8*)(sm + byte);
}
__device__ __forceinline__ s16x8 ldb(const unsigned short* pk, int pkoff, int frag, int lane) {
  return *(const s16x8*)(pk + pkoff + (frag * 64 + lane) * 8);
}

template <int LA, int LB, int LO>
__device__ __forceinline__ void tp_accum(const float* __restrict__ R, float w,
                                         const float* xa, const float* xb, float* sph) {
  constexpr int NA = 2 * LA + 1, NB = 2 * LB + 1, NC = 2 * LO + 1;
#pragma unroll
  for (int a = 0; a < NA; ++a) {
#pragma unroll
    for (int b = 0; b < NB; ++b) {
      float xab = xa[a] * xb[b] * w;
#pragma unroll
      for (int c = 0; c < NC; ++c) sph[c] = fmaf(xab, R[(a * NB + b) * NC + c], sph[c]);
    }
  }
}

__global__ __launch_bounds__(256, 2) void mega_mfma_kernel(
    const float* __restrict__ xs_g, const float* __restrict__ sp_g,
    const int* __restrict__ batch, const float* __restrict__ b1,
    const float* __restrict__ b2, const float* __restrict__ p0,
    const float* __restrict__ p1, const float* __restrict__ p2,
    const float* __restrict__ ws, float* __restrict__ out, int N) {
  __shared__ char sm[SMEM_BYTES];
  float* cg = (float*)(sm + CG_OFF);
  const unsigned short* pk = (const unsigned short*)((const char*)ws + PK_BYTE_OFF);

  const int t = threadIdx.x;
  const int b0 = blockIdx.x * 32;
  const int nb = min(32, N - b0);
  const int lane = t & 63;
  const int wid = t >> 6;

  // ---- stage CG + inputs (bf16, deinterleaved per-m planes, swizzled)
  for (int i = t; i < N_CG_FLOATS; i += 256) cg[i] = ws[i];
  for (int e = t; e < 32 * 128; e += 256) {
    int n = e >> 7, c = e & 127;
    float f = (n < nb) ? xs_g[(long)b0 * 128 + e] : 0.f;
    sw_st16(sm, AS0_OFF, 256, n, c, f2bf(f));
  }
  for (int e = t; e < 32 * 480; e += 256) {
    int n = e / 480, c = e - n * 480;
    float f = (n < nb) ? sp_g[(long)b0 * 480 + e] : 0.f;
    short bv = f2bf(f);
    if (c < 128) {
      sw_st16(sm, ASP0_OFF, 256, n, c, bv);
    } else if (c < 320) {
      int d = c - 128, u = d / 3, m = d - 3 * u;
      sw_st16(sm, ASP1_OFF, 128, m * 32 + n, u, bv);
    } else {
      int d = c - 320, u = d / 5, m = d - 5 * u;
      sw_st16(sm, ASP2_OFF, 64, m * 32 + n, u, bv);
    }
  }
  __syncthreads();

  // ---- GEMM1: h = silu(x_scalar @ A1 + b1) -> Ah (bf16)
  for (int tl = wid; tl < 8; tl += 4) {
    int mt = tl >> 2, nt = tl & 3;
    f32x4 acc = {0.f, 0.f, 0.f, 0.f};
#pragma unroll
    for (int kt = 0; kt < 4; ++kt) {
      s16x8 a = sw_lda(sm, AS0_OFF, 256, mt * 16, kt * 32, lane);
      s16x8 b = ldb(pk, PK_A1, kt * 4 + nt, lane);
      acc = __builtin_amdgcn_mfma_f32_16x16x32_bf16(a, b, acc, 0, 0, 0);
    }
    int col = nt * 16 + (lane & 15);
    int nl0 = mt * 16 + ((lane >> 4) << 2);
    float bb = b1[col];
#pragma unroll
    for (int q = 0; q < 4; ++q) {
      float hv = acc[q] + bb;
      hv = hv / (1.f + __expf(-hv));
      sw_st16(sm, AH_OFF, 128, nl0 + q, col, f2bf(hv));
    }
  }
  __syncthreads();

  // ---- GEMM3/4/5: y (scales folded into packed W) -> y_lds (bf16)
  for (int tl = wid; tl < 4; tl += 4) {  // l=0
    int mt = tl >> 1, nt = tl & 1;
    f32x4 acc = {0.f, 0.f, 0.f, 0.f};
#pragma unroll
    for (int kt = 0; kt < 4; ++kt) {
      s16x8 a = sw_lda(sm, ASP0_OFF, 256, mt * 16, kt * 32, lane);
      s16x8 b = ldb(pk, PK_W0, kt * 2 + nt, lane);
      acc = __builtin_amdgcn_mfma_f32_16x16x32_bf16(a, b, acc, 0, 0, 0);
    }
    int v = nt * 16 + (lane & 15);
    int nl0 = mt * 16 + ((lane >> 4) << 2);
#pragma unroll
    for (int q = 0; q < 4; ++q)
      *(short*)(sm + Y_OFF + (nl0 + q) * 576 + v * 2) = f2bf(acc[q]);
  }
  for (int tl = wid; tl < 12; tl += 4) {  // l=1, rows m*32+n
    int mt = tl >> 1, nt = tl & 1, m = mt >> 1;
    f32x4 acc = {0.f, 0.f, 0.f, 0.f};
#pragma unroll
    for (int kt = 0; kt < 2; ++kt) {
      s16x8 a = sw_lda(sm, ASP1_OFF, 128, mt * 16, kt * 32, lane);
      s16x8 b = ldb(pk, PK_W1, kt * 2 + nt, lane);
      acc = __builtin_amdgcn_mfma_f32_16x16x32_bf16(a, b, acc, 0, 0, 0);
    }
    int v = nt * 16 + (lane & 15);
    int nl0 = (mt & 1) * 16 + ((lane >> 4) << 2);
#pragma unroll
    for (int q = 0; q < 4; ++q)
      *(short*)(sm + Y_OFF + (nl0 + q) * 576 + (32 + m * 32 + v) * 2) = f2bf(acc[q]);
  }
  for (int tl = wid; tl < 20; tl += 4) {  // l=2
    int mt = tl >> 1, nt = tl & 1, m = mt >> 1;
    f32x4 acc = {0.f, 0.f, 0.f, 0.f};
    {
      s16x8 a = sw_lda(sm, ASP2_OFF, 64, mt * 16, 0, lane);
      s16x8 b = ldb(pk, PK_W2, nt, lane);
      acc = __builtin_amdgcn_mfma_f32_16x16x32_bf16(a, b, acc, 0, 0, 0);
    }
    int v = nt * 16 + (lane & 15);
    int nl0 = (mt & 1) * 16 + ((lane >> 4) << 2);
#pragma unroll
    for (int q = 0; q < 4; ++q)
      *(short*)(sm + Y_OFF + (nl0 + q) * 576 + (128 + m * 32 + v) * 2) = f2bf(acc[q]);
  }
  __syncthreads();

  // ---- GEMM2: tp_w = h @ A2 + b2 -> tw (bf16, aliases dead Asp0/Asp1)
  for (int tl = wid; tl < 36; tl += 4) {
    int nt = tl >> 1, mt = tl & 1;
    f32x4 acc = {0.f, 0.f, 0.f, 0.f};
#pragma unroll
    for (int kt = 0; kt < 2; ++kt) {
      s16x8 a = sw_lda(sm, AH_OFF, 128, mt * 16, kt * 32, lane);
      s16x8 b = ldb(pk, PK_A2, kt * 18 + nt, lane);
      acc = __builtin_amdgcn_mfma_f32_16x16x32_bf16(a, b, acc, 0, 0, 0);
    }
    int col = nt * 16 + (lane & 15);
    int nl0 = mt * 16 + ((lane >> 4) << 2);
    float bb = b2[col];
#pragma unroll
    for (int q = 0; q < 4; ++q)
      *(short*)(sm + TW_OFF + (nl0 + q) * 576 + col * 2) = f2bf(acc[q] + bb);
  }
  __syncthreads();

  // ---- RMS + TP + cart + segment-sum (scalar, 4 nodes per thread)
  const int v = t & 31;
  const int s = t >> 5;
  const float invs32 = 0.17677669529663687f;
  const float k0c = invs32 / 3.0f;
  const float k1c = 1.7320508075688772f * invs32 / 2.0f;
  const float k2c = 2.23606797749979f * invs32 / 4.0f;
  const float c0 = k0c * p0[0], c1 = k0c * p0[1], c2 = k0c * p0[2];
  const float c3 = k1c * p1[0], c4 = k1c * p1[1];
  const float c5 = k2c * p2[0], c6 = k2c * p2[1], c7 = k2c * p2[2], c8 = k2c * p2[3];
  const float* qb0 = cg + 357;
  const float* qb1 = cg + 366;
  const float* qb2 = cg + 393;

  for (int r = 0; r < 4; ++r) {
    const int n = s + 8 * r;
    const char* yrow = sm + Y_OFF + n * 576;
    const char* trow = sm + TW_OFF + n * 576;

    float y0v = bf2f(*(const unsigned short*)(yrow + v * 2));
    float y1v[3], y2v[5];
#pragma unroll
    for (int m = 0; m < 3; ++m)
      y1v[m] = bf2f(*(const unsigned short*)(yrow + (32 + m * 32 + v) * 2));
#pragma unroll
    for (int m = 0; m < 5; ++m)
      y2v[m] = bf2f(*(const unsigned short*)(yrow + (128 + m * 32 + v) * 2));

    float s0 = y0v * y0v;
    float s1 = y1v[0] * y1v[0] + y1v[1] * y1v[1] + y1v[2] * y1v[2];
    float s2 = 0.f;
#pragma unroll
    for (int m = 0; m < 5; ++m) s2 = fmaf(y2v[m], y2v[m], s2);
#pragma unroll
    for (int msk = 16; msk >= 1; msk >>= 1) {
      s0 += __shfl_xor(s0, msk);
      s1 += __shfl_xor(s1, msk);
      s2 += __shfl_xor(s2, msk);
    }
    const float i0 = 1.0f / sqrtf(s0 * (1.0f / 32.0f) + 1e-5f);
    const float i1 = 1.0f / sqrtf(s1 * (1.0f / 96.0f) + 1e-5f);
    const float i2 = 1.0f / sqrtf(s2 * (1.0f / 160.0f) + 1e-5f);
    float xs0[1] = {y0v * i0};
    float xs1[3], xs2[5];
#pragma unroll
    for (int m = 0; m < 3; ++m) xs1[m] = y1v[m] * i1;
#pragma unroll
    for (int m = 0; m < 5; ++m) xs2[m] = y2v[m] * i2;

    float w9[9];
#pragma unroll
    for (int i = 0; i < 9; ++i)
      w9[i] = bf2f(*(const unsigned short*)(trow + (i * 32 + v) * 2));

    float sph0[1] = {0.f};
    float sph1[3] = {0.f, 0.f, 0.f};
    float sph2[5] = {0.f, 0.f, 0.f, 0.f, 0.f};
    tp_accum<0, 0, 0>(cg + 0,   w9[0] * c0, xs0, xs0, sph0);
    tp_accum<1, 1, 0>(cg + 1,   w9[1] * c1, xs1, xs1, sph0);
    tp_accum<2, 2, 0>(cg + 10,  w9[2] * c2, xs2, xs2, sph0);
    tp_accum<1, 1, 1>(cg + 35,  w9[3] * c3, xs1, xs1, sph1);
    tp_accum<2, 2, 1>(cg + 62,  w9[4] * c4, xs2, xs2, sph1);
    tp_accum<0, 2, 2>(cg + 137, w9[5] * c5, xs0, xs2, sph2);
    tp_accum<2, 0, 2>(cg + 162, w9[6] * c6, xs2, xs0, sph2);
    tp_accum<1, 1, 2>(cg + 187, w9[7] * c7, xs1, xs1, sph2);
    tp_accum<2, 2, 2>(cg + 232, w9[8] * c8, xs2, xs2, sph2);

#pragma unroll
    for (int msk = 16; msk >= 1; msk >>= 1) {
      sph0[0] += __shfl_xor(sph0[0], msk);
#pragma unroll
      for (int m = 0; m < 3; ++m) sph1[m] += __shfl_xor(sph1[m], msk);
#pragma unroll
      for (int m = 0; m < 5; ++m) sph2[m] += __shfl_xor(sph2[m], msk);
    }

    if (v == 0 && n < nb) {
      float* og = out + (long)batch[b0 + n] * 9;
#pragma unroll
      for (int i = 0; i < 3; ++i) {
#pragma unroll
        for (int j = 0; j < 3; ++j) {
          float val = sph0[0] * qb0[i * 3 + j];
#pragma unroll
          for (int m = 0; m < 3; ++m) val = fmaf(sph1[m], qb1[(i * 3 + j) * 3 + m], val);
#pragma unroll
          for (int m = 0; m < 5; ++m) val = fmaf(sph2[m], qb2[(i * 3 + j) * 5 + m], val);
          atomicAdd(&og[((i + 1) % 3) * 3 + ((j + 1) % 3)], val);
        }
      }
    }
  }
}

// ---------------------------------------------------------------------------

extern "C" void kernel_launch(void* const* d_in, const int* in_sizes, int n_in,
                              void* d_out, int out_size, void* d_ws, size_t ws_size,
                              hipStream_t stream) {
  const float* x_scalar = (const float*)d_in[0];
  const float* x_sph    = (const float*)d_in[1];
  const int*   batch    = (const int*)d_in[2];
  const float* W0 = (const float*)d_in[4];
  const float* W1 = (const float*)d_in[5];
  const float* W2 = (const float*)d_in[6];
  const float* A1 = (const float*)d_in[7];
  const float* b1 = (const float*)d_in[8];
  const float* A2 = (const float*)d_in[9];
  const float* b2 = (const float*)d_in[10];
  const float* p0 = (const float*)d_in[11];
  const float* p1 = (const float*)d_in[12];
  const float* p2 = (const float*)d_in[13];
  float* out = (float*)d_out;
  float* ws  = (float*)d_ws;

  const int N = in_sizes[0] / 128;

  hipMemsetAsync(d_out, 0, (size_t)out_size * sizeof(float), stream);
  setup_cg_par<<<12, 128, 0, stream>>>(ws);
  pack_weights<<<(PK_TOTAL + 255) / 256, 256, 0, stream>>>(A1, W0, W1, W2, A2, ws);
  const int blocks = (N + 31) / 32;
  mega_mfma_kernel<<<blocks, 256, 0, stream>>>(x_scalar, x_sph, batch, b1, b2, p0, p1, p2,
                                               ws, out, N);
}

// Round 5
// 448.750 us; speedup vs baseline: 1.1887x; 1.1887x over previous
//
#include <hip/hip_runtime.h>
#include <math.h>

// ---------------------------------------------------------------------------
// MegaCartTensorOut: fused equivariant TP block, hybrid MFMA + scalar edition.
//
// d_ws layout:
//   floats [0,438): CG tensors + QB
//   bytes [2048, 2048+61440): bf16 weight fragments (A1, W0*1/sqrt128, A2)
// MFMA 16x16x32 bf16, M=16 tiles. Layout facts relied on:
//   - A row / B col = lane&15; k-position = k0 + 8*(lane>>4) + j (consistent
//     permutation on A and B cancels in the contraction)
//   - C/D: col = lane&15, row = 4*(lane>>4)+reg   [HW-verified]
// l=1 / l=2 channel mixes (stride-3/5 layouts) stay scalar with LDS-staged
// f32 weights; x read as aligned b128 chunks from linear bf16 LDS.
// ---------------------------------------------------------------------------

#define N_CG_FLOATS 438

typedef short s16x8 __attribute__((ext_vector_type(8)));
typedef float f32x4 __attribute__((ext_vector_type(4)));

// pk region (units: shorts, from byte 2048 of ws)
#define PK_BYTE_OFF 2048
#define PK_A1 0       // 16 frags (K=128,N=64)
#define PK_W0 8192    // 8  frags (K=128,N=32), scaled 1/sqrt(128)
#define PK_A2 12288   // 36 frags (K=64, N=288)
#define PK_TOTAL 30720

// LDS layout (bytes) — NO aliasing, 44.75 KB total
#define CG_OFF 0        // 438 f32 (1752B, pad to 1792)
#define XS_OFF 1792     // [16][128] bf16, stride 256B, XOR-swizzled
#define SP0_OFF 5888    // [16][128] bf16, stride 256B, XOR-swizzled
#define H_OFF 9984      // [16][64]  bf16, stride 128B, XOR-swizzled
#define Y0_OFF 12032    // [16][32]  bf16, stride 64B, linear
#define TW_OFF 13056    // [16][288] bf16, stride 576B, linear
#define SP12_OFF 22272  // [16][352] bf16, stride 704B, linear
#define W12_OFF 33536   // 3072 f32: W1*0.125 [0,2048), W2/sqrt32 [2048,3072)
#define SMEM_BYTES 45824

__device__ __forceinline__ short f2bf(float f) {
  union { float f; unsigned u; } x; x.f = f;
  unsigned r = (x.u + 0x7FFFu + ((x.u >> 16) & 1u)) >> 16;
  return (short)r;
}
__device__ __forceinline__ float bf2f(unsigned short s) {
  union { unsigned u; float f; } x; x.u = ((unsigned)s) << 16;
  return x.f;
}

// ---------------- CG setup (verified rounds 1-4) -----------------------------

__device__ __forceinline__ double dfact(int n) {
  double r = 1.0;
  for (int i = 2; i <= n; ++i) r *= (double)i;
  return r;
}

__device__ __forceinline__ void u_elem(int l, int i, int j, double& re, double& im) {
  re = 0.0; im = 0.0;
  const int mr = i - l, mc = j - l;
  const double is2 = 0.70710678118654752440;
  if (mr == 0) { if (mc == 0) re = 1.0; }
  else if (mr > 0) {
    if (mc == mr) re = ((mr & 1) ? -1.0 : 1.0) * is2;
    else if (mc == -mr) re = is2;
  } else {
    int m = -mr;
    if (mc == m) im = -(((m & 1) ? -1.0 : 1.0)) * is2;
    else if (mc == -m) im = is2;
  }
}

__global__ void setup_cg_par(float* __restrict__ ws) {
  const int LAs[12] = {0, 1, 2, 1, 2, 0, 2, 1, 2, 1, 1, 1};
  const int LBs[12] = {0, 1, 2, 1, 2, 2, 0, 1, 2, 1, 1, 1};
  const int LOs[12] = {0, 0, 0, 1, 1, 2, 2, 2, 2, 0, 1, 2};
  const int OFF[12] = {0, 1, 10, 35, 62, 137, 162, 187, 232, 357, 366, 393};

  const int blk = blockIdx.x;
  const int l1 = LAs[blk], l2 = LBs[blk], l3 = LOs[blk];
  const double scale = (blk >= 9) ? sqrt(2.0 * l3 + 1.0) : 1.0;
  const int n1 = 2 * l1 + 1, n2 = 2 * l2 + 1, n3 = 2 * l3 + 1;
  const int nel = n1 * n2 * n3;
  const int t = threadIdx.x;

  __shared__ double Cs[125];
  __shared__ double Rre[125], Rim[125];
  __shared__ double s_inv;
  __shared__ int s_useRe;

  if (t < nel) {
    const int i3 = t % n3, i2 = (t / n3) % n2, i1 = t / (n3 * n2);
    const int m1 = i1 - l1, m2 = i2 - l2, m3 = i3 - l3;
    double val = 0.0;
    if (m1 + m2 == m3) {
      double pre = sqrt((2.0 * l3 + 1.0) * dfact(l1 + l2 - l3) * dfact(l1 - l2 + l3) *
                        dfact(-l1 + l2 + l3) / dfact(l1 + l2 + l3 + 1));
      pre *= sqrt(dfact(l3 + m3) * dfact(l3 - m3) * dfact(l1 - m1) * dfact(l1 + m1) *
                  dfact(l2 - m2) * dfact(l2 + m2));
      double s = 0.0;
      for (int k = 0; k <= l1 + l2 - l3; ++k) {
        int d1 = l1 + l2 - l3 - k, d2 = l1 - m1 - k, d3 = l2 + m2 - k;
        int d4 = l3 - l2 + m1 + k, d5 = l3 - l1 - m2 + k;
        if (d1 < 0 || d2 < 0 || d3 < 0 || d4 < 0 || d5 < 0) continue;
        double prod = dfact(k) * dfact(d1) * dfact(d2) * dfact(d3) * dfact(d4) * dfact(d5);
        s += ((k & 1) ? -1.0 : 1.0) / prod;
      }
      val = pre * s;
    }
    Cs[t] = val;
  }
  __syncthreads();

  if (t < nel) {
    const int c = t % n3, bb = (t / n3) % n2, a = t / (n3 * n2);
    double sr_ = 0.0, si_ = 0.0;
    for (int m = 0; m < n1; ++m) {
      double u1r, u1i;
      u_elem(l1, a, m, u1r, u1i);
      if (u1r == 0.0 && u1i == 0.0) continue;
      for (int nn = 0; nn < n2; ++nn) {
        double u2r, u2i;
        u_elem(l2, bb, nn, u2r, u2i);
        double t12r = u1r * u2r - u1i * u2i;
        double t12i = u1r * u2i + u1i * u2r;
        if (t12r == 0.0 && t12i == 0.0) continue;
        for (int o = 0; o < n3; ++o) {
          double cgv = Cs[(m * n2 + nn) * n3 + o];
          if (cgv == 0.0) continue;
          double u3r, u3i;
          u_elem(l3, c, o, u3r, u3i);
          sr_ += (t12r * u3r + t12i * u3i) * cgv;
          si_ += (t12i * u3r - t12r * u3i) * cgv;
        }
      }
    }
    Rre[t] = sr_;
    Rim[t] = si_;
  }
  __syncthreads();

  if (t == 0) {
    double maxRe = 0.0, maxIm = 0.0;
    for (int e = 0; e < nel; ++e) {
      maxRe = fmax(maxRe, fabs(Rre[e]));
      maxIm = fmax(maxIm, fabs(Rim[e]));
    }
    int useRe = (maxRe >= maxIm) ? 1 : 0;
    double nrm = 0.0;
    for (int e = 0; e < nel; ++e) {
      double vv = useRe ? Rre[e] : Rim[e];
      nrm += vv * vv;
    }
    s_useRe = useRe;
    s_inv = scale / sqrt(nrm);
  }
  __syncthreads();

  if (t < nel) {
    double vv = s_useRe ? Rre[t] : Rim[t];
    ws[OFF[blk] + t] = (float)(vv * s_inv);
  }
}

// ---------------- weight fragment packing ------------------------------------
// B [K][N] row-major -> frag(kt,nt): lane l, j: B[kt*32+8*(l>>4)+j][nt*16+(l&15)]
__global__ void pack_weights(const float* __restrict__ A1, const float* __restrict__ W0,
                             const float* __restrict__ A2, float* __restrict__ ws) {
  unsigned short* pk = (unsigned short*)((char*)ws + PK_BYTE_OFF);
  int e = blockIdx.x * 256 + threadIdx.x;
  if (e >= PK_TOTAL) return;
  const float* src;
  int Ncols, off;
  float scale;
  if (e < PK_W0)      { src = A1; Ncols = 64;  off = PK_A1; scale = 1.f; }
  else if (e < PK_A2) { src = W0; Ncols = 32;  off = PK_W0; scale = 0.08838834764831845f; }
  else                { src = A2; Ncols = 288; off = PK_A2; scale = 1.f; }
  int local = e - off;
  int frag = local >> 9;
  int l = (local >> 3) & 63;
  int j = local & 7;
  int ntn = Ncols >> 4;
  int kt = frag / ntn, nt = frag - kt * ntn;
  int k = kt * 32 + 8 * (l >> 4) + j;
  int c = nt * 16 + (l & 15);
  pk[e] = (unsigned short)f2bf(src[k * Ncols + c] * scale);
}

// ---------------- main fused kernel ------------------------------------------

__device__ __forceinline__ s16x8 cvt8(const float* __restrict__ g) {
  float4 a = *(const float4*)g;
  float4 b = *(const float4*)(g + 4);
  s16x8 r;
  r[0] = f2bf(a.x); r[1] = f2bf(a.y); r[2] = f2bf(a.z); r[3] = f2bf(a.w);
  r[4] = f2bf(b.x); r[5] = f2bf(b.y); r[6] = f2bf(b.z); r[7] = f2bf(b.w);
  return r;
}

__device__ __forceinline__ void sw_wr8(char* sm, int base, int strideB, int r, int c0, s16x8 v) {
  int byte = base + r * strideB + c0 * 2;
  byte ^= (r & 7) << 4;
  *(s16x8*)(sm + byte) = v;
}
__device__ __forceinline__ s16x8 sw_lda16(const char* sm, int base, int strideB, int k0,
                                          int lane) {
  int r = lane & 15;
  int byte = base + r * strideB + (k0 + 8 * (lane >> 4)) * 2;
  byte ^= (r & 7) << 4;
  return *(const s16x8*)(sm + byte);
}

template <int LA, int LB, int LO>
__device__ __forceinline__ void tp_accum(const float* __restrict__ R, float w,
                                         const float* xa, const float* xb, float* sph) {
  constexpr int NA = 2 * LA + 1, NB = 2 * LB + 1, NC = 2 * LO + 1;
#pragma unroll
  for (int a = 0; a < NA; ++a) {
#pragma unroll
    for (int b = 0; b < NB; ++b) {
      float xab = xa[a] * xb[b] * w;
#pragma unroll
      for (int c = 0; c < NC; ++c) sph[c] = fmaf(xab, R[(a * NB + b) * NC + c], sph[c]);
    }
  }
}

__global__ __launch_bounds__(256) void mega_kernel(
    const float* __restrict__ xs_g, const float* __restrict__ sp_g,
    const int* __restrict__ batch, const float* __restrict__ W1g,
    const float* __restrict__ W2g, const float* __restrict__ b1,
    const float* __restrict__ b2, const float* __restrict__ p0,
    const float* __restrict__ p1, const float* __restrict__ p2,
    const float* __restrict__ ws, float* __restrict__ out, int N) {
  __shared__ char sm[SMEM_BYTES];
  float* cg = (float*)(sm + CG_OFF);
  float* w12f = (float*)(sm + W12_OFF);
  const unsigned short* pk = (const unsigned short*)((const char*)ws + PK_BYTE_OFF);

  const int t = threadIdx.x;
  const int b0 = blockIdx.x * 16;
  const int lane = t & 63;
  const int wid = t >> 6;

  // ---- staging (all b128 LDS writes; reads coalesced float4)
  for (int i = t; i < N_CG_FLOATS; i += 256) cg[i] = ws[i];
  {
    int n = t >> 4, c0 = (t & 15) * 8;
    long nn = min(b0 + n, N - 1);
    sw_wr8(sm, XS_OFF, 256, n, c0, cvt8(xs_g + nn * 128 + c0));
    sw_wr8(sm, SP0_OFF, 256, n, c0, cvt8(sp_g + nn * 480 + c0));
  }
  for (int i = t; i < 704; i += 256) {
    int n = i / 44, j = i - n * 44;
    long nn = min(b0 + n, N - 1);
    s16x8 v = cvt8(sp_g + nn * 480 + 128 + j * 8);
    *(s16x8*)(sm + SP12_OFF + n * 704 + j * 16) = v;
  }
  for (int i = t; i < 768; i += 256) {
    float4 f;
    float scl;
    if (i < 512) { f = ((const float4*)W1g)[i]; scl = 0.125f; }
    else         { f = ((const float4*)W2g)[i - 512]; scl = 0.17677669529663687f; }
    float4 o;
    o.x = f.x * scl; o.y = f.y * scl; o.z = f.z * scl; o.w = f.w * scl;
    ((float4*)(sm + W12_OFF))[i] = o;
  }
  __syncthreads();

  // ---- GEMM1: h = silu(x_scalar @ A1 + b1); wave wid owns nt=wid
  {
    const int nt = wid;
    f32x4 acc = {0.f, 0.f, 0.f, 0.f};
#pragma unroll
    for (int kt = 0; kt < 4; ++kt) {
      s16x8 a = sw_lda16(sm, XS_OFF, 256, kt * 32, lane);
      s16x8 b = *(const s16x8*)(pk + PK_A1 + ((kt * 4 + nt) * 64 + lane) * 8);
      acc = __builtin_amdgcn_mfma_f32_16x16x32_bf16(a, b, acc, 0, 0, 0);
    }
    const int col = nt * 16 + (lane & 15);
    const int r0 = (lane >> 4) * 4;
    const float bb = b1[col];
#pragma unroll
    for (int q = 0; q < 4; ++q) {
      float hv = acc[q] + bb;
      hv = hv / (1.f + __expf(-hv));
      int r = r0 + q;
      int byte = H_OFF + r * 128 + col * 2;
      byte ^= (r & 7) << 4;
      *(short*)(sm + byte) = f2bf(hv);
    }
  }
  __syncthreads();

  // ---- GEMM-W0 (2 tiles) + GEMM-A2 (18 tiles): 20 tiles over 4 waves
  for (int tl = wid; tl < 20; tl += 4) {
    f32x4 acc = {0.f, 0.f, 0.f, 0.f};
    if (tl < 2) {
      const int nt = tl;
#pragma unroll
      for (int kt = 0; kt < 4; ++kt) {
        s16x8 a = sw_lda16(sm, SP0_OFF, 256, kt * 32, lane);
        s16x8 b = *(const s16x8*)(pk + PK_W0 + ((kt * 2 + nt) * 64 + lane) * 8);
        acc = __builtin_amdgcn_mfma_f32_16x16x32_bf16(a, b, acc, 0, 0, 0);
      }
      const int col = nt * 16 + (lane & 15);
      const int r0 = (lane >> 4) * 4;
#pragma unroll
      for (int q = 0; q < 4; ++q)
        *(short*)(sm + Y0_OFF + (r0 + q) * 64 + col * 2) = f2bf(acc[q]);
    } else {
      const int nt = tl - 2;
#pragma unroll
      for (int kt = 0; kt < 2; ++kt) {
        s16x8 a = sw_lda16(sm, H_OFF, 128, kt * 32, lane);
        s16x8 b = *(const s16x8*)(pk + PK_A2 + ((kt * 18 + nt) * 64 + lane) * 8);
        acc = __builtin_amdgcn_mfma_f32_16x16x32_bf16(a, b, acc, 0, 0, 0);
      }
      const int col = nt * 16 + (lane & 15);
      const int r0 = (lane >> 4) * 4;
      const float bb = b2[col];
#pragma unroll
      for (int q = 0; q < 4; ++q)
        *(short*)(sm + TW_OFF + (r0 + q) * 576 + col * 2) = f2bf(acc[q] + bb);
    }
  }
  __syncthreads();

  // ---- scalar phase: l1/l2 mixes + RMS + TP + cart + segment-sum
  const int v = t & 31;
  const int s = t >> 5;
  const float invs32 = 0.17677669529663687f;
  const float k0c = invs32 / 3.0f;
  const float k1c = 1.7320508075688772f * invs32 / 2.0f;
  const float k2c = 2.23606797749979f * invs32 / 4.0f;
  const float c0 = k0c * p0[0], c1 = k0c * p0[1], c2 = k0c * p0[2];
  const float c3 = k1c * p1[0], c4 = k1c * p1[1];
  const float c5 = k2c * p2[0], c6 = k2c * p2[1], c7 = k2c * p2[2], c8 = k2c * p2[3];
  const float* qb0 = cg + 357;
  const float* qb1 = cg + 366;
  const float* qb2 = cg + 393;

  for (int r = 0; r < 2; ++r) {
    const int n = s + 8 * r;
    const char* sp12n = sm + SP12_OFF + n * 704;

    // y1[m] = sum_u x1[n][u][m] * W1[u][v] * 0.125  (x via aligned b128 chunks)
    float y1[3] = {0.f, 0.f, 0.f};
#pragma unroll
    for (int q = 0; q < 8; ++q) {
      s16x8 e0 = *(const s16x8*)(sp12n + q * 48);
      s16x8 e1 = *(const s16x8*)(sp12n + q * 48 + 16);
      s16x8 e2 = *(const s16x8*)(sp12n + q * 48 + 32);
      float xv[24];
#pragma unroll
      for (int k = 0; k < 8; ++k) {
        xv[k]      = bf2f((unsigned short)e0[k]);
        xv[8 + k]  = bf2f((unsigned short)e1[k]);
        xv[16 + k] = bf2f((unsigned short)e2[k]);
      }
#pragma unroll
      for (int uu = 0; uu < 8; ++uu) {
        float w = w12f[(q * 8 + uu) * 32 + v];
        y1[0] = fmaf(xv[uu * 3 + 0], w, y1[0]);
        y1[1] = fmaf(xv[uu * 3 + 1], w, y1[1]);
        y1[2] = fmaf(xv[uu * 3 + 2], w, y1[2]);
      }
    }

    // y2[m] = sum_u x2[n][u][m] * W2[u][v] / sqrt(32)
    float y2[5] = {0.f, 0.f, 0.f, 0.f, 0.f};
#pragma unroll
    for (int q = 0; q < 4; ++q) {
      const char* base = sp12n + 384 + q * 80;
      s16x8 e0 = *(const s16x8*)(base);
      s16x8 e1 = *(const s16x8*)(base + 16);
      s16x8 e2 = *(const s16x8*)(base + 32);
      s16x8 e3 = *(const s16x8*)(base + 48);
      s16x8 e4 = *(const s16x8*)(base + 64);
      float xv[40];
#pragma unroll
      for (int k = 0; k < 8; ++k) {
        xv[k]      = bf2f((unsigned short)e0[k]);
        xv[8 + k]  = bf2f((unsigned short)e1[k]);
        xv[16 + k] = bf2f((unsigned short)e2[k]);
        xv[24 + k] = bf2f((unsigned short)e3[k]);
        xv[32 + k] = bf2f((unsigned short)e4[k]);
      }
#pragma unroll
      for (int uu = 0; uu < 8; ++uu) {
        float w = w12f[2048 + (q * 8 + uu) * 32 + v];
#pragma unroll
        for (int m = 0; m < 5; ++m) y2[m] = fmaf(xv[uu * 5 + m], w, y2[m]);
      }
    }

    const float y0v = bf2f(*(const unsigned short*)(sm + Y0_OFF + n * 64 + v * 2));

    // RMS over the 32 channel lanes
    float s0 = y0v * y0v;
    float s1 = y1[0] * y1[0] + y1[1] * y1[1] + y1[2] * y1[2];
    float s2 = 0.f;
#pragma unroll
    for (int m = 0; m < 5; ++m) s2 = fmaf(y2[m], y2[m], s2);
#pragma unroll
    for (int msk = 16; msk >= 1; msk >>= 1) {
      s0 += __shfl_xor(s0, msk);
      s1 += __shfl_xor(s1, msk);
      s2 += __shfl_xor(s2, msk);
    }
    const float i0 = 1.0f / sqrtf(s0 * (1.0f / 32.0f) + 1e-5f);
    const float i1 = 1.0f / sqrtf(s1 * (1.0f / 96.0f) + 1e-5f);
    const float i2 = 1.0f / sqrtf(s2 * (1.0f / 160.0f) + 1e-5f);
    float xs0[1] = {y0v * i0};
    float xs1[3], xs2[5];
#pragma unroll
    for (int m = 0; m < 3; ++m) xs1[m] = y1[m] * i1;
#pragma unroll
    for (int m = 0; m < 5; ++m) xs2[m] = y2[m] * i2;

    float w9[9];
#pragma unroll
    for (int i = 0; i < 9; ++i)
      w9[i] = bf2f(*(const unsigned short*)(sm + TW_OFF + n * 576 + (i * 32 + v) * 2));

    float sph0[1] = {0.f};
    float sph1[3] = {0.f, 0.f, 0.f};
    float sph2[5] = {0.f, 0.f, 0.f, 0.f, 0.f};
    tp_accum<0, 0, 0>(cg + 0,   w9[0] * c0, xs0, xs0, sph0);
    tp_accum<1, 1, 0>(cg + 1,   w9[1] * c1, xs1, xs1, sph0);
    tp_accum<2, 2, 0>(cg + 10,  w9[2] * c2, xs2, xs2, sph0);
    tp_accum<1, 1, 1>(cg + 35,  w9[3] * c3, xs1, xs1, sph1);
    tp_accum<2, 2, 1>(cg + 62,  w9[4] * c4, xs2, xs2, sph1);
    tp_accum<0, 2, 2>(cg + 137, w9[5] * c5, xs0, xs2, sph2);
    tp_accum<2, 0, 2>(cg + 162, w9[6] * c6, xs2, xs0, sph2);
    tp_accum<1, 1, 2>(cg + 187, w9[7] * c7, xs1, xs1, sph2);
    tp_accum<2, 2, 2>(cg + 232, w9[8] * c8, xs2, xs2, sph2);

#pragma unroll
    for (int msk = 16; msk >= 1; msk >>= 1) {
      sph0[0] += __shfl_xor(sph0[0], msk);
#pragma unroll
      for (int m = 0; m < 3; ++m) sph1[m] += __shfl_xor(sph1[m], msk);
#pragma unroll
      for (int m = 0; m < 5; ++m) sph2[m] += __shfl_xor(sph2[m], msk);
    }

    if (v == 0 && b0 + n < N) {
      float* og = out + (long)batch[b0 + n] * 9;
#pragma unroll
      for (int i = 0; i < 3; ++i) {
#pragma unroll
        for (int j = 0; j < 3; ++j) {
          float val = sph0[0] * qb0[i * 3 + j];
#pragma unroll
          for (int m = 0; m < 3; ++m) val = fmaf(sph1[m], qb1[(i * 3 + j) * 3 + m], val);
#pragma unroll
          for (int m = 0; m < 5; ++m) val = fmaf(sph2[m], qb2[(i * 3 + j) * 5 + m], val);
          atomicAdd(&og[((i + 1) % 3) * 3 + ((j + 1) % 3)], val);
        }
      }
    }
  }
}

// ---------------------------------------------------------------------------

extern "C" void kernel_launch(void* const* d_in, const int* in_sizes, int n_in,
                              void* d_out, int out_size, void* d_ws, size_t ws_size,
                              hipStream_t stream) {
  const float* x_scalar = (const float*)d_in[0];
  const float* x_sph    = (const float*)d_in[1];
  const int*   batch    = (const int*)d_in[2];
  const float* W0 = (const float*)d_in[4];
  const float* W1 = (const float*)d_in[5];
  const float* W2 = (const float*)d_in[6];
  const float* A1 = (const float*)d_in[7];
  const float* b1 = (const float*)d_in[8];
  const float* A2 = (const float*)d_in[9];
  const float* b2 = (const float*)d_in[10];
  const float* p0 = (const float*)d_in[11];
  const float* p1 = (const float*)d_in[12];
  const float* p2 = (const float*)d_in[13];
  float* out = (float*)d_out;
  float* ws  = (float*)d_ws;

  const int N = in_sizes[0] / 128;

  hipMemsetAsync(d_out, 0, (size_t)out_size * sizeof(float), stream);
  setup_cg_par<<<12, 128, 0, stream>>>(ws);
  pack_weights<<<(PK_TOTAL + 255) / 256, 256, 0, stream>>>(A1, W0, A2, ws);
  const int blocks = (N + 15) / 16;
  mega_kernel<<<blocks, 256, 0, stream>>>(x_scalar, x_sph, batch, W1, W2, b1, b2, p0, p1, p2,
                                          ws, out, N);
}